// Round 1
// baseline (1644.289 us; speedup 1.0000x reference)
//
#include <hip/hip_runtime.h>
#include <hip/hip_bf16.h>

// Problem constants
#define BB 16
#define NN 4096
#define CC 768
#define HH 12
#define HD 64
#define SCALE_F 0.125f

typedef unsigned short u16;
typedef __bf16 bf16x8 __attribute__((ext_vector_type(8)));
typedef float f32x4 __attribute__((ext_vector_type(4)));
typedef u16 u16x4 __attribute__((ext_vector_type(4)));

__device__ __forceinline__ u16 f2bf(float f) {
  union { __hip_bfloat16 h; u16 u; } v;
  v.h = __float2bfloat16(f);
  return v.u;
}

__device__ __forceinline__ float bf2f(u16 u) {
  union { unsigned int i; float f; } v;
  v.i = ((unsigned int)u) << 16;
  return v.f;
}

// split f into bf16 hi + bf16 lo (hi+lo captures ~16-17 mantissa bits)
__device__ __forceinline__ void split2(float f, u16& hi, u16& lo) {
  hi = f2bf(f);
  lo = f2bf(f - bf2f(hi));
}

__device__ __forceinline__ f32x4 mfma16(bf16x8 a, bf16x8 b, f32x4 c) {
  return __builtin_amdgcn_mfma_f32_16x16x32_bf16(a, b, c, 0, 0, 0);
}

union bfr_u { bf16x8 v; u16 u[8]; };

// load 8 contiguous fp32 and split into hi/lo bf16x8 fragments
__device__ __forceinline__ void load_split8(const float* p, bf16x8& hi, bf16x8& lo) {
  f32x4 v0 = *(const f32x4*)p;
  f32x4 v1 = *(const f32x4*)(p + 4);
  bfr_u h, l;
  for (int i = 0; i < 4; i++) split2(v0[i], h.u[i], l.u[i]);
  for (int i = 0; i < 4; i++) split2(v1[i], h.u[4 + i], l.u[4 + i]);
  hi = h.v; lo = l.v;
}

// ---------------------------------------------------------------------------
// Kernel X: one-time cast X fp32 -> bf16 (both modalities).
// Hoists the f2bf conversion that gram re-did 6x per panel and out re-did once.
// ---------------------------------------------------------------------------
__global__ __launch_bounds__(256) void xcast_kernel(const float* __restrict__ x0,
                                                    const float* __restrict__ x1,
                                                    u16* __restrict__ Xb) {
  const size_t total = (size_t)BB * NN * CC;  // 50,331,648 per modality
  const float* X = blockIdx.y ? x1 : x0;
  u16* O = Xb + (size_t)blockIdx.y * total;
  size_t i = ((size_t)blockIdx.x * 256 + threadIdx.x) * 8;
  const size_t step = (size_t)gridDim.x * 256 * 8;  // 4096*256*8 = 8,388,608 -> exactly 6 iters
  for (; i < total; i += step) {
    f32x4 a = *(const f32x4*)(X + i);
    f32x4 b = *(const f32x4*)(X + i + 4);
    bfr_u h;
    for (int j = 0; j < 4; j++) h.u[j] = f2bf(a[j]);
    for (int j = 0; j < 4; j++) h.u[4 + j] = f2bf(b[j]);
    *(bf16x8*)&O[i] = h.v;
  }
}

// ---------------------------------------------------------------------------
// Kernel 0: transpose + cast W [768][1536] fp32 -> WT_hi/WT_lo [1536][768] bf16
// ---------------------------------------------------------------------------
__global__ __launch_bounds__(256) void wtrans_kernel(const float* __restrict__ w0,
                                                     const float* __restrict__ w1,
                                                     u16* __restrict__ WTh,
                                                     u16* __restrict__ WTl) {
  __shared__ float tile[64][65];
  const float* W = blockIdx.z ? w1 : w0;
  const size_t obase = (size_t)blockIdx.z * (1536 * 768);
  const int col0 = blockIdx.x * 64;  // 24 tiles
  const int c0   = blockIdx.y * 64;  // 12 tiles
  const int t = threadIdx.x;
  const int lc = t & 63;
  const int lr = t >> 6;
  for (int r = lr; r < 64; r += 4)
    tile[r][lc] = W[(size_t)(c0 + r) * 1536 + col0 + lc];  // tile[c_off][col_off]
  __syncthreads();
  for (int r = lr; r < 64; r += 4) {
    u16 hi, lo;
    split2(tile[lc][r], hi, lo);
    WTh[obase + (size_t)(col0 + r) * CC + c0 + lc] = hi;
    WTl[obase + (size_t)(col0 + r) * CC + c0 + lc] = lo;
  }
}

// ---------------------------------------------------------------------------
// Kernel 1: per-batch Gram G_b = X_b^T X_b  (bf16 MFMA, symmetric: 21 tile-pairs)
// Now consumes pre-cast bf16 X: staging is pure load+repack (no cvt),
// 128 threads stage A, 128 stage B (half the loads/thread vs fp32 version).
// LDS tile layout (transposed, swizzled) unchanged:
//   addr_u16(c,k) = (c>>2)*168 + (c&3)*8 + (k>>3)*32 + (k&7),  c in [0,128), k in [0,32)
// ---------------------------------------------------------------------------
__device__ __forceinline__ int gtile_addr(int c, int k) {
  return (c >> 2) * 168 + (c & 3) * 8 + (k >> 3) * 32 + (k & 7);
}

__global__ __launch_bounds__(256) void gram_kernel(const u16* __restrict__ Xb,
                                                   u16* __restrict__ Gh,
                                                   u16* __restrict__ Gl) {
  __shared__ u16 As[32 * 168];
  __shared__ u16 Bs[32 * 168];

  int idx = blockIdx.x;  // 0..20 -> (ti,tj) with ti<=tj, 6x6 tiles
  int ti = 0;
  while (idx >= 6 - ti) { idx -= 6 - ti; ti++; }
  const int tj = ti + idx;
  const int b = blockIdx.y, modal = blockIdx.z;
  const u16* X = Xb + (size_t)(modal * BB + b) * NN * CC;
  const size_t goff = (size_t)(modal * BB + b) * CC * CC;
  u16* Ghb = Gh + goff;
  u16* Glb = Gl + goff;

  const int t = threadIdx.x;
  const int lane = t & 63;
  const int w = t >> 6;
  const int lm = lane & 15;
  const int q = lane >> 4;
  const int wm = (w & 1) * 64;
  const int wn = (w >> 1) * 64;

  const bool diag = (ti == tj);

  // Staging roles: threads 0..127 stage A (ti panel), 128..255 stage B (tj panel).
  // Each stager: 4 rows x 8 cols = 4x 16B loads, 8x 8B transposed LDS writes.
  const int tt = t & 127;
  const int sc0 = (tt & 15) * 8;   // c chunk base, 16 chunks cover 128 cols
  const int snb = (tt >> 4) * 4;   // row base, 8 groups cover 32 rows
  const bool isB = (t >= 128);
  const int tile0 = (isB ? tj : ti) * 128;
  u16* T = isB ? Bs : As;
  const bool do_stage = !(isB && diag);

  f32x4 acc[4][4];
  for (int i = 0; i < 4; i++)
    for (int j = 0; j < 4; j++) { f32x4 z = {0.f, 0.f, 0.f, 0.f}; acc[i][j] = z; }

  for (int kc = 0; kc < NN / 32; kc++) {
    const int n0 = kc * 32;
    __syncthreads();
    if (do_stage) {
      const u16* src = X + (size_t)(n0 + snb) * CC + tile0 + sc0;
      bfr_u r0, r1, r2, r3;
      r0.v = *(const bf16x8*)(src);
      r1.v = *(const bf16x8*)(src + CC);
      r2.v = *(const bf16x8*)(src + 2 * CC);
      r3.v = *(const bf16x8*)(src + 3 * CC);
#pragma unroll
      for (int i = 0; i < 8; i++) {
        u16x4 p = {r0.u[i], r1.u[i], r2.u[i], r3.u[i]};
        *(u16x4*)&T[gtile_addr(sc0 + i, snb)] = p;
      }
    }
    __syncthreads();
    const u16* Bp = diag ? As : Bs;
    bf16x8 af[4], bfr[4];
    for (int mt = 0; mt < 4; mt++)
      af[mt] = *(const bf16x8*)&As[gtile_addr(wm + mt * 16 + lm, q * 8)];
    for (int nt = 0; nt < 4; nt++)
      bfr[nt] = *(const bf16x8*)&Bp[gtile_addr(wn + nt * 16 + lm, q * 8)];
    for (int mt = 0; mt < 4; mt++)
      for (int nt = 0; nt < 4; nt++)
        acc[mt][nt] = mfma16(af[mt], bfr[nt], acc[mt][nt]);
  }

  // Epilogue: C/D layout col=lane&15, row=4*q+reg; store split hi/lo
  for (int mt = 0; mt < 4; mt++)
    for (int nt = 0; nt < 4; nt++) {
      const int row0 = ti * 128 + wm + mt * 16 + q * 4;
      const int col  = tj * 128 + wn + nt * 16 + lm;
      f32x4 v = acc[mt][nt];
      u16 hi[4], lo[4];
      for (int i = 0; i < 4; i++) split2(v[i], hi[i], lo[i]);
      for (int i = 0; i < 4; i++) {
        Ghb[(size_t)(row0 + i) * CC + col] = hi[i];
        Glb[(size_t)(row0 + i) * CC + col] = lo[i];
      }
      if (!diag) {  // mirror block (G symmetric)
        u16x4 ph = {hi[0], hi[1], hi[2], hi[3]};
        u16x4 pl = {lo[0], lo[1], lo[2], lo[3]};
        *(u16x4*)&Ghb[(size_t)col * CC + row0] = ph;
        *(u16x4*)&Glb[(size_t)col * CC + row0] = pl;
      }
    }
}

// ---------------------------------------------------------------------------
// Kernel 2: per (b,h,modal): ctx = softmax_d( SCALE * Wk_h^T G_b Wv_h )
// Split-bf16 (3-chain) MFMA throughout; U kept fp32 in LDS; 4 r-passes of 192.
// ctx stored TRANSPOSED [e][d] bf16.
// ---------------------------------------------------------------------------
__global__ __launch_bounds__(256) void ctx_kernel(const u16* __restrict__ WTh,
                                                  const u16* __restrict__ WTl,
                                                  const u16* __restrict__ Gh,
                                                  const u16* __restrict__ Gl,
                                                  u16* __restrict__ ctxT) {
  __shared__ __align__(16) float Us[64 * 196];  // 50176 B; [e][r_local], stride 196
  float* cs = Us;                               // later aliased: logits [d][e], stride 68

  const int h = blockIdx.x, b = blockIdx.y, modal = blockIdx.z;
  const size_t goff = (size_t)(modal * BB + b) * CC * CC;
  const u16* Ghb = Gh + goff;
  const u16* Glb = Gl + goff;
  const size_t vrow = (size_t)modal * 1536 + 768 + h * HD;  // Wv^T rows [e][c]
  const size_t krow = (size_t)modal * 1536 + h * HD;        // Wk^T rows [d][c]
  u16* cout = ctxT + ((size_t)((modal * BB + b) * HH + h)) * (HD * HD);

  const int t = threadIdx.x;
  const int lane = t & 63, w = t >> 6;
  const int lm = lane & 15, q = lane >> 4;
  const int d0 = w * 16;  // stage-2 m-tile per wave

  f32x4 acc2[4];
  for (int i = 0; i < 4; i++) { f32x4 z = {0.f, 0.f, 0.f, 0.f}; acc2[i] = z; }

  for (int p = 0; p < 4; p++) {
    const int rbase = p * 192;
    __syncthreads();  // protect Us from previous pass stage-2 readers
    // Stage 1: U[r][e] = sum_c G[r][c] * Wv[c][e], r-local in [0,192)
    for (int mi = 0; mi < 3; mi++) {
      const int row0 = w * 48 + mi * 16;
      const size_t r = (size_t)(rbase + row0 + lm) * CC;
      f32x4 acc[4];
      for (int i = 0; i < 4; i++) { f32x4 z = {0.f, 0.f, 0.f, 0.f}; acc[i] = z; }
      for (int kc = 0; kc < 24; kc++) {
        const int co = kc * 32 + q * 8;
        bf16x8 ah = *(const bf16x8*)&Ghb[r + co];
        bf16x8 al = *(const bf16x8*)&Glb[r + co];
        for (int nt = 0; nt < 4; nt++) {
          bf16x8 bh = *(const bf16x8*)&WTh[(vrow + nt * 16 + lm) * CC + co];
          bf16x8 bl = *(const bf16x8*)&WTl[(vrow + nt * 16 + lm) * CC + co];
          acc[nt] = mfma16(ah, bh, acc[nt]);
          acc[nt] = mfma16(al, bh, acc[nt]);
          acc[nt] = mfma16(ah, bl, acc[nt]);
        }
      }
      for (int nt = 0; nt < 4; nt++)  // D: row=q*4+i -> r_local, col=lm -> e
        *(f32x4*)&Us[(nt * 16 + lm) * 196 + row0 + q * 4] = acc[nt];
    }
    __syncthreads();
    // Stage 2 partial accumulate: ctx[d][e] += sum_{r in pass} Wk[r][d] * U[r][e]
    for (int rc = 0; rc < 6; rc++) {
      bf16x8 ah = *(const bf16x8*)&WTh[(krow + d0 + lm) * CC + rbase + rc * 32 + q * 8];
      bf16x8 al = *(const bf16x8*)&WTl[(krow + d0 + lm) * CC + rbase + rc * 32 + q * 8];
      for (int nt = 0; nt < 4; nt++) {
        bf16x8 bh, bl;
        load_split8(&Us[(nt * 16 + lm) * 196 + rc * 32 + q * 8], bh, bl);
        acc2[nt] = mfma16(ah, bh, acc2[nt]);
        acc2[nt] = mfma16(al, bh, acc2[nt]);
        acc2[nt] = mfma16(ah, bl, acc2[nt]);
      }
    }
  }
  __syncthreads();  // everyone done reading Us before aliasing as cs
  for (int nt = 0; nt < 4; nt++) {
    const int e = nt * 16 + lm;
    for (int i = 0; i < 4; i++)
      cs[(d0 + q * 4 + i) * 68 + e] = acc2[nt][i] * SCALE_F;
  }
  __syncthreads();
  if (t < 64) {
    const int e = t;
    float mx = -1e30f;
    for (int d = 0; d < 64; d++) mx = fmaxf(mx, cs[d * 68 + e]);
    float s = 0.f;
    for (int d = 0; d < 64; d++) s += __expf(cs[d * 68 + e] - mx);
    const float inv = 1.f / s;
    for (int d = 0; d < 64; d++)
      cout[e * 64 + d] = f2bf(__expf(cs[d * 68 + e] - mx) * inv);  // [e][d]
  }
}

// ---------------------------------------------------------------------------
// Kernel 3: out[modal][b, n, h*64+e] = sum_d X_modal[b,n,h*64+d] * ctx[modal^1][b,h,d,e]
// 32 rows per workgroup; X now pre-cast bf16: staging is a pure 16B copy.
// ---------------------------------------------------------------------------
__global__ __launch_bounds__(256) void out_kernel(const u16* __restrict__ Xb,
                                                  const u16* __restrict__ ctxT,
                                                  float* __restrict__ out) {
  __shared__ u16 Xs[32 * 776];  // 49664 u16
  const int nt0 = blockIdx.x;   // 128 tiles of 32 rows
  const int b = blockIdx.y, modal = blockIdx.z;
  const u16* X = Xb + (size_t)(modal * BB + b) * NN * CC + (size_t)nt0 * 32 * CC;
  const u16* ctxb = ctxT + (size_t)(((modal ^ 1) * BB + b) * HH) * (HD * HD);
  float* O = out + (size_t)modal * BB * NN * CC + (size_t)b * NN * CC + (size_t)nt0 * 32 * CC;

  const int t = threadIdx.x;
  for (int idx = t; idx < 32 * 96; idx += 256) {  // 8 bf16 per step, 12 iters
    const int r = idx / 96, c8 = idx % 96;
    *(bf16x8*)&Xs[r * 776 + c8 * 8] = *(const bf16x8*)&X[(size_t)r * CC + c8 * 8];
  }
  __syncthreads();

  const int lane = t & 63, w = t >> 6;
  const int lm = lane & 15, q = lane >> 4;
  const int mt = w & 1;          // row-tile 0/1 (16 rows each)
  const int hh = (w >> 1) * 6;   // head base
  for (int hi = 0; hi < 6; hi++) {
    const int h = hh + hi;
    bf16x8 a0 = *(const bf16x8*)&Xs[(mt * 16 + lm) * 776 + h * 64 + 0 + q * 8];
    bf16x8 a1 = *(const bf16x8*)&Xs[(mt * 16 + lm) * 776 + h * 64 + 32 + q * 8];
    const u16* ch = ctxb + (size_t)h * (HD * HD);  // [e][d]
    for (int et = 0; et < 4; et++) {
      f32x4 acc = {0.f, 0.f, 0.f, 0.f};
      bf16x8 b0 = *(const bf16x8*)&ch[(et * 16 + lm) * 64 + 0 + q * 8];
      bf16x8 b1 = *(const bf16x8*)&ch[(et * 16 + lm) * 64 + 32 + q * 8];
      acc = mfma16(a0, b0, acc);
      acc = mfma16(a1, b1, acc);
      for (int i = 0; i < 4; i++)
        O[(size_t)(mt * 16 + q * 4 + i) * CC + h * 64 + et * 16 + lm] = acc[i];
    }
  }
}

// ---------------------------------------------------------------------------
extern "C" void kernel_launch(void* const* d_in, const int* in_sizes, int n_in,
                              void* d_out, int out_size, void* d_ws, size_t ws_size,
                              hipStream_t stream) {
  (void)in_sizes; (void)n_in; (void)out_size; (void)ws_size;
  const float* rgb   = (const float*)d_in[0];
  const float* dep   = (const float*)d_in[1];
  const float* w_rgb = (const float*)d_in[2];
  const float* w_dep = (const float*)d_in[3];
  float* out = (float*)d_out;

  char* ws = (char*)d_ws;
  u16* WTh = (u16*)ws;                       // 2*1536*768*2  = 4,718,592 B
  u16* WTl = (u16*)(ws + 4718592);           // 4,718,592 B
  u16* Gh  = (u16*)(ws + 9437184);           // 2*16*768*768*2 = 37,748,736 B
  u16* Gl  = (u16*)(ws + 47185920);          // 37,748,736 B
  u16* CT  = (u16*)(ws + 84934656);          // 2*16*12*64*64*2 = 3,145,728 B
  u16* Xbf = (u16*)(ws + 88080384);          // 2*16*4096*768*2 = 201,326,592 B
                                             // total 289,406,976 B

  xcast_kernel<<<dim3(4096, 2), 256, 0, stream>>>(rgb, dep, Xbf);
  wtrans_kernel<<<dim3(24, 12, 2), 256, 0, stream>>>(w_rgb, w_dep, WTh, WTl);
  gram_kernel<<<dim3(21, 16, 2), 256, 0, stream>>>(Xbf, Gh, Gl);
  ctx_kernel<<<dim3(HH, BB, 2), 256, 0, stream>>>(WTh, WTl, Gh, Gl, CT);
  out_kernel<<<dim3(128, BB, 2), 256, 0, stream>>>(Xbf, CT, out);
}

// Round 2
// 1157.731 us; speedup vs baseline: 1.4203x; 1.4203x over previous
//
#include <hip/hip_runtime.h>
#include <hip/hip_bf16.h>

// Problem constants
#define BB 16
#define NN 4096
#define CC 768
#define HH 12
#define HD 64
#define SCALE_F 0.125f

typedef unsigned short u16;
typedef unsigned int u32;
typedef __bf16 bf16x8 __attribute__((ext_vector_type(8)));
typedef float f32x4 __attribute__((ext_vector_type(4)));
typedef u16 u16x4 __attribute__((ext_vector_type(4)));

__device__ __forceinline__ u16 f2bf(float f) {
  union { __hip_bfloat16 h; u16 u; } v;
  v.h = __float2bfloat16(f);
  return v.u;
}

__device__ __forceinline__ float bf2f(u16 u) {
  union { unsigned int i; float f; } v;
  v.i = ((unsigned int)u) << 16;
  return v.f;
}

// split f into bf16 hi + bf16 lo (hi+lo captures ~16-17 mantissa bits)
__device__ __forceinline__ void split2(float f, u16& hi, u16& lo) {
  hi = f2bf(f);
  lo = f2bf(f - bf2f(hi));
}

__device__ __forceinline__ f32x4 mfma16(bf16x8 a, bf16x8 b, f32x4 c) {
  return __builtin_amdgcn_mfma_f32_16x16x32_bf16(a, b, c, 0, 0, 0);
}

union bfr_u { bf16x8 v; u16 u[8]; };

// load 8 contiguous fp32 and split into hi/lo bf16x8 fragments
__device__ __forceinline__ void load_split8(const float* p, bf16x8& hi, bf16x8& lo) {
  f32x4 v0 = *(const f32x4*)p;
  f32x4 v1 = *(const f32x4*)(p + 4);
  bfr_u h, l;
  for (int i = 0; i < 4; i++) split2(v0[i], h.u[i], l.u[i]);
  for (int i = 0; i < 4; i++) split2(v1[i], h.u[4 + i], l.u[4 + i]);
  hi = h.v; lo = l.v;
}

// async global->LDS 16B: per-lane global src, wave-uniform LDS base (+lane*16 by HW)
__device__ __forceinline__ void gl_lds16(const u16* gsrc, u16* ldst) {
  __builtin_amdgcn_global_load_lds(
      (const __attribute__((address_space(1))) u32*)gsrc,
      (__attribute__((address_space(3))) u32*)ldst, 16, 0, 0);
}

// ---------------------------------------------------------------------------
// Kernel X: one-time cast X fp32 -> bf16 (both modalities).
// ---------------------------------------------------------------------------
__global__ __launch_bounds__(256) void xcast_kernel(const float* __restrict__ x0,
                                                    const float* __restrict__ x1,
                                                    u16* __restrict__ Xb) {
  const size_t total = (size_t)BB * NN * CC;  // 50,331,648 per modality
  const float* X = blockIdx.y ? x1 : x0;
  u16* O = Xb + (size_t)blockIdx.y * total;
  size_t i = ((size_t)blockIdx.x * 256 + threadIdx.x) * 8;
  const size_t step = (size_t)gridDim.x * 256 * 8;
  for (; i < total; i += step) {
    f32x4 a = *(const f32x4*)(X + i);
    f32x4 b = *(const f32x4*)(X + i + 4);
    bfr_u h;
    for (int j = 0; j < 4; j++) h.u[j] = f2bf(a[j]);
    for (int j = 0; j < 4; j++) h.u[4 + j] = f2bf(b[j]);
    *(bf16x8*)&O[i] = h.v;
  }
}

// ---------------------------------------------------------------------------
// Kernel 0: transpose + cast W [768][1536] fp32 -> WT_hi/WT_lo [1536][768] bf16
// ---------------------------------------------------------------------------
__global__ __launch_bounds__(256) void wtrans_kernel(const float* __restrict__ w0,
                                                     const float* __restrict__ w1,
                                                     u16* __restrict__ WTh,
                                                     u16* __restrict__ WTl) {
  __shared__ float tile[64][65];
  const float* W = blockIdx.z ? w1 : w0;
  const size_t obase = (size_t)blockIdx.z * (1536 * 768);
  const int col0 = blockIdx.x * 64;  // 24 tiles
  const int c0   = blockIdx.y * 64;  // 12 tiles
  const int t = threadIdx.x;
  const int lc = t & 63;
  const int lr = t >> 6;
  for (int r = lr; r < 64; r += 4)
    tile[r][lc] = W[(size_t)(c0 + r) * 1536 + col0 + lc];
  __syncthreads();
  for (int r = lr; r < 64; r += 4) {
    u16 hi, lo;
    split2(tile[lc][r], hi, lo);
    WTh[obase + (size_t)(col0 + r) * CC + c0 + lc] = hi;
    WTl[obase + (size_t)(col0 + r) * CC + c0 + lc] = lo;
  }
}

// ---------------------------------------------------------------------------
// Kernel 1: per-batch Gram G_b = X_b^T X_b  (bf16 MFMA, symmetric: 21 tile-pairs)
// XCD-swizzled 1-D grid (672 = 8 xcd * 4 groups * 21 tiles): all 21 tiles of a
// (b,modal) land on one XCD -> X panels + G stay L2-local.
// ---------------------------------------------------------------------------
__device__ __forceinline__ int gtile_addr(int c, int k) {
  return (c >> 2) * 168 + (c & 3) * 8 + (k >> 3) * 32 + (k & 7);
}

__global__ __launch_bounds__(256) void gram_kernel(const u16* __restrict__ Xb,
                                                   u16* __restrict__ Gh,
                                                   u16* __restrict__ Gl) {
  __shared__ u16 As[32 * 168];
  __shared__ u16 Bs[32 * 168];

  // XCD-aware decode (bijective): dd -> (xcd, j); g = (j/21)*8 + xcd; i = j%21
  const int dd = blockIdx.x;
  const int j = dd >> 3;
  const int g = (j / 21) * 8 + (dd & 7);
  int idx = j % 21;
  const int b = g & 15, modal = g >> 4;

  int ti = 0;
  while (idx >= 6 - ti) { idx -= 6 - ti; ti++; }
  const int tj = ti + idx;
  const u16* X = Xb + (size_t)(modal * BB + b) * NN * CC;
  const size_t goff = (size_t)(modal * BB + b) * CC * CC;
  u16* Ghb = Gh + goff;
  u16* Glb = Gl + goff;

  const int t = threadIdx.x;
  const int lane = t & 63;
  const int w = t >> 6;
  const int lm = lane & 15;
  const int q = lane >> 4;
  const int wm = (w & 1) * 64;
  const int wn = (w >> 1) * 64;

  const bool diag = (ti == tj);

  const int tt = t & 127;
  const int sc0 = (tt & 15) * 8;   // c chunk base
  const int snb = (tt >> 4) * 4;   // row base
  const bool isB = (t >= 128);
  const int tile0 = (isB ? tj : ti) * 128;
  u16* T = isB ? Bs : As;
  const bool do_stage = !(isB && diag);

  f32x4 acc[4][4];
  for (int i = 0; i < 4; i++)
    for (int jj = 0; jj < 4; jj++) { f32x4 z = {0.f, 0.f, 0.f, 0.f}; acc[i][jj] = z; }

  for (int kc = 0; kc < NN / 32; kc++) {
    const int n0 = kc * 32;
    __syncthreads();
    if (do_stage) {
      const u16* src = X + (size_t)(n0 + snb) * CC + tile0 + sc0;
      bfr_u r0, r1, r2, r3;
      r0.v = *(const bf16x8*)(src);
      r1.v = *(const bf16x8*)(src + CC);
      r2.v = *(const bf16x8*)(src + 2 * CC);
      r3.v = *(const bf16x8*)(src + 3 * CC);
#pragma unroll
      for (int i = 0; i < 8; i++) {
        u16x4 p = {r0.u[i], r1.u[i], r2.u[i], r3.u[i]};
        *(u16x4*)&T[gtile_addr(sc0 + i, snb)] = p;
      }
    }
    __syncthreads();
    const u16* Bp = diag ? As : Bs;
    bf16x8 af[4], bfr[4];
    for (int mt = 0; mt < 4; mt++)
      af[mt] = *(const bf16x8*)&As[gtile_addr(wm + mt * 16 + lm, q * 8)];
    for (int nt = 0; nt < 4; nt++)
      bfr[nt] = *(const bf16x8*)&Bp[gtile_addr(wn + nt * 16 + lm, q * 8)];
    for (int mt = 0; mt < 4; mt++)
      for (int nt = 0; nt < 4; nt++)
        acc[mt][nt] = mfma16(af[mt], bfr[nt], acc[mt][nt]);
  }

  for (int mt = 0; mt < 4; mt++)
    for (int nt = 0; nt < 4; nt++) {
      const int row0 = ti * 128 + wm + mt * 16 + q * 4;
      const int col  = tj * 128 + wn + nt * 16 + lm;
      f32x4 v = acc[mt][nt];
      u16 hi[4], lo[4];
      for (int i = 0; i < 4; i++) split2(v[i], hi[i], lo[i]);
      for (int i = 0; i < 4; i++) {
        Ghb[(size_t)(row0 + i) * CC + col] = hi[i];
        Glb[(size_t)(row0 + i) * CC + col] = lo[i];
      }
      if (!diag) {
        u16x4 ph = {hi[0], hi[1], hi[2], hi[3]};
        u16x4 pl = {lo[0], lo[1], lo[2], lo[3]};
        *(u16x4*)&Ghb[(size_t)col * CC + row0] = ph;
        *(u16x4*)&Glb[(size_t)col * CC + row0] = pl;
      }
    }
}

// ---------------------------------------------------------------------------
// Kernel 2a (ctx1): per (b,modal): U = G_b @ Wv_all  (768x768x768, 3-chain split)
// 128x128 tiles, K-step 64, global_load_lds staging with XOR-swizzle
// (k-group ^ (row&7)): linear LDS dest + pre-swizzled global source (rule #21).
// Output stored TRANSPOSED: UT[e][r] fp32 (so ctx2's B-operand is row-major).
// Grid: 1152 blocks, XCD-swizzled (36 tiles of a (b,modal) share an XCD).
// ---------------------------------------------------------------------------
__global__ __launch_bounds__(256) void ctx1_kernel(const u16* __restrict__ WTh,
                                                   const u16* __restrict__ WTl,
                                                   const u16* __restrict__ Gh,
                                                   const u16* __restrict__ Gl,
                                                   float* __restrict__ UT) {
  __shared__ __align__(16) u16 lds[32768];  // 64 KB: Ah|Al|Bh|Bl, each [128][64]

  const int dd = blockIdx.x;
  const int j = dd >> 3;
  const int g = (j / 36) * 8 + (dd & 7);  // (b,modal) group 0..31
  const int i = j % 36;
  const int b = g & 15, modal = g >> 4;
  const int ti = i / 6, tj = i % 6;       // r-tile, e-tile

  const size_t goff = (size_t)(modal * BB + b) * CC * CC;
  const u16* Ghb = Gh + goff;
  const u16* Glb = Gl + goff;
  const int vbase = modal * 1536 + 768 + tj * 128;  // WT rows holding Wv^T
  float* UTb = UT + (size_t)(modal * BB + b) * CC * CC;

  const int t = threadIdx.x;
  const int lane = t & 63, w = t >> 6;
  const int lm = lane & 15, q = lane >> 4;
  const int wm = (w & 1) * 64, wn = (w >> 1) * 64;

  // staging: wave w stages component w (0=Ah 1=Al 2=Bh 3=Bl), 16x 1KB instrs
  const int srow = lane >> 3;          // 0..7 within 8-row group
  const int sg = (lane & 7) ^ srow;    // pre-swizzled k-group (involution)
  const u16* comp_src;
  if (w < 2) comp_src = (w == 0 ? Ghb : Glb) + (size_t)(ti * 128 + srow) * CC + sg * 8;
  else       comp_src = (w == 2 ? WTh : WTl) + (size_t)(vbase + srow) * CC + sg * 8;
  u16* comp_dst = &lds[w * 8192];

  f32x4 acc[4][4];
  for (int mt = 0; mt < 4; mt++)
    for (int nt = 0; nt < 4; nt++) { f32x4 z = {0.f, 0.f, 0.f, 0.f}; acc[mt][nt] = z; }

  for (int kc = 0; kc < 12; kc++) {
    __syncthreads();
#pragma unroll
    for (int ii = 0; ii < 16; ii++)
      gl_lds16(comp_src + (size_t)ii * 8 * CC + kc * 64, comp_dst + ii * 512);
    __syncthreads();  // drains vmcnt before readers cross
#pragma unroll
    for (int kk = 0; kk < 2; kk++) {
      bf16x8 ah[4], al_[4], bh[4], bl_[4];
      const int gq8 = ((kk * 4 + q) ^ (lm & 7)) * 8;
#pragma unroll
      for (int mt = 0; mt < 4; mt++) {
        const int ro = (wm + mt * 16 + lm) * 64;
        ah[mt]  = *(const bf16x8*)&lds[ro + gq8];
        al_[mt] = *(const bf16x8*)&lds[8192 + ro + gq8];
      }
#pragma unroll
      for (int nt = 0; nt < 4; nt++) {
        const int ro = (wn + nt * 16 + lm) * 64;
        bh[nt]  = *(const bf16x8*)&lds[16384 + ro + gq8];
        bl_[nt] = *(const bf16x8*)&lds[24576 + ro + gq8];
      }
#pragma unroll
      for (int mt = 0; mt < 4; mt++)
#pragma unroll
        for (int nt = 0; nt < 4; nt++) {
          acc[mt][nt] = mfma16(ah[mt], bh[nt], acc[mt][nt]);
          acc[mt][nt] = mfma16(al_[mt], bh[nt], acc[mt][nt]);
          acc[mt][nt] = mfma16(ah[mt], bl_[nt], acc[mt][nt]);
        }
    }
  }

  // epilogue: UT[e][r] = acc (C/D: row=m=r-local=q*4+i, col=n=e-local=lm)
  for (int mt = 0; mt < 4; mt++)
    for (int nt = 0; nt < 4; nt++) {
      const int e = tj * 128 + wn + nt * 16 + lm;
      const int r0 = ti * 128 + wm + mt * 16 + q * 4;
      *(f32x4*)&UTb[(size_t)e * CC + r0] = acc[mt][nt];
    }
}

// ---------------------------------------------------------------------------
// Kernel 2b (ctx2): per (b,h,modal): logits = Wk_h^T @ U_h (64x64, K=768),
// split-on-load from fp32 UT; scale; softmax over d; ctxT[e][d] bf16.
// ---------------------------------------------------------------------------
__global__ __launch_bounds__(256) void ctx2_kernel(const u16* __restrict__ WTh,
                                                   const u16* __restrict__ WTl,
                                                   const float* __restrict__ UT,
                                                   u16* __restrict__ ctxT) {
  __shared__ float cs[64 * 68];
  const int h = blockIdx.x, b = blockIdx.y, modal = blockIdx.z;
  const float* UTb = UT + (size_t)(modal * BB + b) * CC * CC;
  const size_t krow = (size_t)modal * 1536 + h * HD;
  u16* cout = ctxT + ((size_t)((modal * BB + b) * HH + h)) * (HD * HD);

  const int t = threadIdx.x;
  const int lane = t & 63, w = t >> 6;
  const int lm = lane & 15, q = lane >> 4;
  const int d0 = w * 16;

  f32x4 acc[4];
  for (int i = 0; i < 4; i++) { f32x4 z = {0.f, 0.f, 0.f, 0.f}; acc[i] = z; }

  const u16* akh = &WTh[(krow + d0 + lm) * CC];
  const u16* akl = &WTl[(krow + d0 + lm) * CC];
  const float* ub = &UTb[(size_t)(h * HD) * CC];
  for (int rc = 0; rc < 24; rc++) {
    const int co = rc * 32 + q * 8;
    bf16x8 ah = *(const bf16x8*)&akh[co];
    bf16x8 al = *(const bf16x8*)&akl[co];
#pragma unroll
    for (int nt = 0; nt < 4; nt++) {
      bf16x8 bh, bl;
      load_split8(&ub[(size_t)(nt * 16 + lm) * CC + co], bh, bl);
      acc[nt] = mfma16(ah, bh, acc[nt]);
      acc[nt] = mfma16(al, bh, acc[nt]);
      acc[nt] = mfma16(ah, bl, acc[nt]);
    }
  }
  // logits: row=m=d-local=q*4+i, col=n=e-local=lm
  for (int nt = 0; nt < 4; nt++) {
    const int e = nt * 16 + lm;
    for (int i = 0; i < 4; i++)
      cs[(d0 + q * 4 + i) * 68 + e] = acc[nt][i] * SCALE_F;
  }
  __syncthreads();
  if (t < 64) {
    const int e = t;
    float mx = -1e30f;
    for (int d = 0; d < 64; d++) mx = fmaxf(mx, cs[d * 68 + e]);
    float s = 0.f;
    for (int d = 0; d < 64; d++) s += __expf(cs[d * 68 + e] - mx);
    const float inv = 1.f / s;
    for (int d = 0; d < 64; d++)
      cout[e * 64 + d] = f2bf(__expf(cs[d * 68 + e] - mx) * inv);  // [e][d]
  }
}

// ---------------------------------------------------------------------------
// Fallback ctx (old fused kernel) — used only if workspace too small for UT.
// ---------------------------------------------------------------------------
__global__ __launch_bounds__(256) void ctx_kernel(const u16* __restrict__ WTh,
                                                  const u16* __restrict__ WTl,
                                                  const u16* __restrict__ Gh,
                                                  const u16* __restrict__ Gl,
                                                  u16* __restrict__ ctxT) {
  __shared__ __align__(16) float Us[64 * 196];
  float* cs = Us;

  const int h = blockIdx.x, b = blockIdx.y, modal = blockIdx.z;
  const size_t goff = (size_t)(modal * BB + b) * CC * CC;
  const u16* Ghb = Gh + goff;
  const u16* Glb = Gl + goff;
  const size_t vrow = (size_t)modal * 1536 + 768 + h * HD;
  const size_t krow = (size_t)modal * 1536 + h * HD;
  u16* cout = ctxT + ((size_t)((modal * BB + b) * HH + h)) * (HD * HD);

  const int t = threadIdx.x;
  const int lane = t & 63, w = t >> 6;
  const int lm = lane & 15, q = lane >> 4;
  const int d0 = w * 16;

  f32x4 acc2[4];
  for (int i = 0; i < 4; i++) { f32x4 z = {0.f, 0.f, 0.f, 0.f}; acc2[i] = z; }

  for (int p = 0; p < 4; p++) {
    const int rbase = p * 192;
    __syncthreads();
    for (int mi = 0; mi < 3; mi++) {
      const int row0 = w * 48 + mi * 16;
      const size_t r = (size_t)(rbase + row0 + lm) * CC;
      f32x4 acc[4];
      for (int i = 0; i < 4; i++) { f32x4 z = {0.f, 0.f, 0.f, 0.f}; acc[i] = z; }
      for (int kc = 0; kc < 24; kc++) {
        const int co = kc * 32 + q * 8;
        bf16x8 ah = *(const bf16x8*)&Ghb[r + co];
        bf16x8 al = *(const bf16x8*)&Glb[r + co];
        for (int nt = 0; nt < 4; nt++) {
          bf16x8 bh = *(const bf16x8*)&WTh[(vrow + nt * 16 + lm) * CC + co];
          bf16x8 bl = *(const bf16x8*)&WTl[(vrow + nt * 16 + lm) * CC + co];
          acc[nt] = mfma16(ah, bh, acc[nt]);
          acc[nt] = mfma16(al, bh, acc[nt]);
          acc[nt] = mfma16(ah, bl, acc[nt]);
        }
      }
      for (int nt = 0; nt < 4; nt++)
        *(f32x4*)&Us[(nt * 16 + lm) * 196 + row0 + q * 4] = acc[nt];
    }
    __syncthreads();
    for (int rc = 0; rc < 6; rc++) {
      bf16x8 ah = *(const bf16x8*)&WTh[(krow + d0 + lm) * CC + rbase + rc * 32 + q * 8];
      bf16x8 al = *(const bf16x8*)&WTl[(krow + d0 + lm) * CC + rbase + rc * 32 + q * 8];
      for (int nt = 0; nt < 4; nt++) {
        bf16x8 bh, bl;
        load_split8(&Us[(nt * 16 + lm) * 196 + rc * 32 + q * 8], bh, bl);
        acc2[nt] = mfma16(ah, bh, acc2[nt]);
        acc2[nt] = mfma16(al, bh, acc2[nt]);
        acc2[nt] = mfma16(ah, bl, acc2[nt]);
      }
    }
  }
  __syncthreads();
  for (int nt = 0; nt < 4; nt++) {
    const int e = nt * 16 + lm;
    for (int i = 0; i < 4; i++)
      cs[(d0 + q * 4 + i) * 68 + e] = acc2[nt][i] * SCALE_F;
  }
  __syncthreads();
  if (t < 64) {
    const int e = t;
    float mx = -1e30f;
    for (int d = 0; d < 64; d++) mx = fmaxf(mx, cs[d * 68 + e]);
    float s = 0.f;
    for (int d = 0; d < 64; d++) s += __expf(cs[d * 68 + e] - mx);
    const float inv = 1.f / s;
    for (int d = 0; d < 64; d++)
      cout[e * 64 + d] = f2bf(__expf(cs[d * 68 + e] - mx) * inv);
  }
}

// ---------------------------------------------------------------------------
// Kernel 3: out[modal][b, n, h*64+e] = sum_d X_modal[b,n,h*64+d] * ctx[modal^1][b,h,d,e]
// ---------------------------------------------------------------------------
__global__ __launch_bounds__(256) void out_kernel(const u16* __restrict__ Xb,
                                                  const u16* __restrict__ ctxT,
                                                  float* __restrict__ out) {
  __shared__ u16 Xs[32 * 776];
  const int nt0 = blockIdx.x;
  const int b = blockIdx.y, modal = blockIdx.z;
  const u16* X = Xb + (size_t)(modal * BB + b) * NN * CC + (size_t)nt0 * 32 * CC;
  const u16* ctxb = ctxT + (size_t)(((modal ^ 1) * BB + b) * HH) * (HD * HD);
  float* O = out + (size_t)modal * BB * NN * CC + (size_t)b * NN * CC + (size_t)nt0 * 32 * CC;

  const int t = threadIdx.x;
  for (int idx = t; idx < 32 * 96; idx += 256) {
    const int r = idx / 96, c8 = idx % 96;
    *(bf16x8*)&Xs[r * 776 + c8 * 8] = *(const bf16x8*)&X[(size_t)r * CC + c8 * 8];
  }
  __syncthreads();

  const int lane = t & 63, w = t >> 6;
  const int lm = lane & 15, q = lane >> 4;
  const int mt = w & 1;
  const int hh = (w >> 1) * 6;
  for (int hi = 0; hi < 6; hi++) {
    const int h = hh + hi;
    bf16x8 a0 = *(const bf16x8*)&Xs[(mt * 16 + lm) * 776 + h * 64 + 0 + q * 8];
    bf16x8 a1 = *(const bf16x8*)&Xs[(mt * 16 + lm) * 776 + h * 64 + 32 + q * 8];
    const u16* ch = ctxb + (size_t)h * (HD * HD);
    for (int et = 0; et < 4; et++) {
      f32x4 acc = {0.f, 0.f, 0.f, 0.f};
      bf16x8 b0 = *(const bf16x8*)&ch[(et * 16 + lm) * 64 + 0 + q * 8];
      bf16x8 b1 = *(const bf16x8*)&ch[(et * 16 + lm) * 64 + 32 + q * 8];
      acc = mfma16(a0, b0, acc);
      acc = mfma16(a1, b1, acc);
      for (int i = 0; i < 4; i++)
        O[(size_t)(mt * 16 + q * 4 + i) * CC + h * 64 + et * 16 + lm] = acc[i];
    }
  }
}

// ---------------------------------------------------------------------------
extern "C" void kernel_launch(void* const* d_in, const int* in_sizes, int n_in,
                              void* d_out, int out_size, void* d_ws, size_t ws_size,
                              hipStream_t stream) {
  (void)in_sizes; (void)n_in; (void)out_size;
  const float* rgb   = (const float*)d_in[0];
  const float* dep   = (const float*)d_in[1];
  const float* w_rgb = (const float*)d_in[2];
  const float* w_dep = (const float*)d_in[3];
  float* out = (float*)d_out;

  char* ws = (char*)d_ws;
  u16* WTh = (u16*)ws;                       // 4,718,592 B
  u16* WTl = (u16*)(ws + 4718592);           // 4,718,592 B
  u16* Gh  = (u16*)(ws + 9437184);           // 37,748,736 B
  u16* Gl  = (u16*)(ws + 47185920);          // 37,748,736 B
  u16* CT  = (u16*)(ws + 84934656);          // 3,145,728 B
  u16* Xbf = (u16*)(ws + 88080384);          // 201,326,592 B  (end: 289,406,976)
  const size_t UT_OFF = 289406976ull;
  const size_t WS_NEED = UT_OFF + 75497472ull;  // + UT fp32 = 364,904,448 B

  xcast_kernel<<<dim3(4096, 2), 256, 0, stream>>>(rgb, dep, Xbf);
  wtrans_kernel<<<dim3(24, 12, 2), 256, 0, stream>>>(w_rgb, w_dep, WTh, WTl);
  gram_kernel<<<dim3(672, 1, 1), 256, 0, stream>>>(Xbf, Gh, Gl);
  if (ws_size >= WS_NEED) {
    float* UT = (float*)(ws + UT_OFF);
    ctx1_kernel<<<dim3(1152, 1, 1), 256, 0, stream>>>(WTh, WTl, Gh, Gl, UT);
    ctx2_kernel<<<dim3(HH, BB, 2), 256, 0, stream>>>(WTh, WTl, UT, CT);
  } else {
    ctx_kernel<<<dim3(HH, BB, 2), 256, 0, stream>>>(WTh, WTl, Gh, Gl, CT);
  }
  out_kernel<<<dim3(128, BB, 2), 256, 0, stream>>>(Xbf, CT, out);
}

// Round 3
// 1131.311 us; speedup vs baseline: 1.4534x; 1.0234x over previous
//
#include <hip/hip_runtime.h>
#include <hip/hip_bf16.h>

// Problem constants
#define BB 16
#define NN 4096
#define CC 768
#define HH 12
#define HD 64
#define SCALE_F 0.125f

typedef unsigned short u16;
typedef unsigned int u32;
typedef __bf16 bf16x8 __attribute__((ext_vector_type(8)));
typedef float f32x4 __attribute__((ext_vector_type(4)));
typedef u16 u16x4 __attribute__((ext_vector_type(4)));

__device__ __forceinline__ u16 f2bf(float f) {
  union { __hip_bfloat16 h; u16 u; } v;
  v.h = __float2bfloat16(f);
  return v.u;
}

__device__ __forceinline__ float bf2f(u16 u) {
  union { unsigned int i; float f; } v;
  v.i = ((unsigned int)u) << 16;
  return v.f;
}

// split f into bf16 hi + bf16 lo (hi+lo captures ~16-17 mantissa bits)
__device__ __forceinline__ void split2(float f, u16& hi, u16& lo) {
  hi = f2bf(f);
  lo = f2bf(f - bf2f(hi));
}

__device__ __forceinline__ f32x4 mfma16(bf16x8 a, bf16x8 b, f32x4 c) {
  return __builtin_amdgcn_mfma_f32_16x16x32_bf16(a, b, c, 0, 0, 0);
}

union bfr_u { bf16x8 v; u16 u[8]; };

// async global->LDS 16B: per-lane global src, wave-uniform LDS base (+lane*16 by HW)
__device__ __forceinline__ void gl_lds16(const u16* gsrc, u16* ldst) {
  __builtin_amdgcn_global_load_lds(
      (const __attribute__((address_space(1))) u32*)gsrc,
      (__attribute__((address_space(3))) u32*)ldst, 16, 0, 0);
}

// ---------------------------------------------------------------------------
// Kernel X: cast + TRANSPOSE X fp32 [n][c] -> XbT bf16 [c][n] (both modalities).
// LDS 64x65 fp32 tile transpose (conflict-free both directions).
// ---------------------------------------------------------------------------
__global__ __launch_bounds__(256) void xcastT_kernel(const float* __restrict__ x0,
                                                     const float* __restrict__ x1,
                                                     u16* __restrict__ XbT) {
  __shared__ float tile[64][65];
  const int z = blockIdx.z;  // modal*BB + b
  const int b = z & 15, modal = z >> 4;
  const float* X = (modal ? x1 : x0) + (size_t)b * NN * CC;
  u16* O = XbT + (size_t)z * CC * NN;
  const int n0 = blockIdx.x * 64;  // 64 tiles
  const int c0 = blockIdx.y * 64;  // 12 tiles
  const int t = threadIdx.x;
  const int lc = t & 63, lr = t >> 6;
  for (int r = lr; r < 64; r += 4)
    tile[r][lc] = X[(size_t)(n0 + r) * CC + c0 + lc];
  __syncthreads();
  for (int r = lr; r < 64; r += 4)
    O[(size_t)(c0 + r) * NN + n0 + lc] = f2bf(tile[lc][r]);
}

// ---------------------------------------------------------------------------
// Kernel 0: transpose + cast W [768][1536] fp32 -> WT_hi/WT_lo [1536][768] bf16
// ---------------------------------------------------------------------------
__global__ __launch_bounds__(256) void wtrans_kernel(const float* __restrict__ w0,
                                                     const float* __restrict__ w1,
                                                     u16* __restrict__ WTh,
                                                     u16* __restrict__ WTl) {
  __shared__ float tile[64][65];
  const float* W = blockIdx.z ? w1 : w0;
  const size_t obase = (size_t)blockIdx.z * (1536 * 768);
  const int col0 = blockIdx.x * 64;  // 24 tiles
  const int c0   = blockIdx.y * 64;  // 12 tiles
  const int t = threadIdx.x;
  const int lc = t & 63;
  const int lr = t >> 6;
  for (int r = lr; r < 64; r += 4)
    tile[r][lc] = W[(size_t)(c0 + r) * 1536 + col0 + lc];
  __syncthreads();
  for (int r = lr; r < 64; r += 4) {
    u16 hi, lo;
    split2(tile[lc][r], hi, lo);
    WTh[obase + (size_t)(col0 + r) * CC + c0 + lc] = hi;
    WTl[obase + (size_t)(col0 + r) * CC + c0 + lc] = lo;
  }
}

// ---------------------------------------------------------------------------
// Kernel 1: per-batch Gram G_b = X_b^T X_b  (bf16 MFMA, symmetric: 21 tile-pairs)
// v2: reads XbT [c][n] -> staging is pure global_load_lds(16B) into linear LDS
// with XOR-swizzled global source (k-group ^= row&7); conflict-free ds_read_b128.
// BK=64 (64 K-steps). XCD-swizzled 1-D grid (672 = 8 xcd * 4 groups * 21 tiles).
// ---------------------------------------------------------------------------
__global__ __launch_bounds__(256) void gram_kernel(const u16* __restrict__ XbT,
                                                   u16* __restrict__ Gh,
                                                   u16* __restrict__ Gl) {
  __shared__ __align__(16) u16 As[128 * 64];  // 16 KB
  __shared__ __align__(16) u16 Bs[128 * 64];  // 16 KB

  // XCD-aware decode (bijective): dd -> (xcd, j); g = (j/21)*8 + xcd; i = j%21
  const int dd = blockIdx.x;
  const int j = dd >> 3;
  const int g = (j / 21) * 8 + (dd & 7);
  int idx = j % 21;
  const int b = g & 15, modal = g >> 4;

  int ti = 0;
  while (idx >= 6 - ti) { idx -= 6 - ti; ti++; }
  const int tj = ti + idx;
  const bool diag = (ti == tj);

  const u16* Xbm = XbT + (size_t)(modal * BB + b) * CC * NN;
  const size_t goff = (size_t)(modal * BB + b) * CC * CC;
  u16* Ghb = Gh + goff;
  u16* Glb = Gl + goff;

  const int t = threadIdx.x;
  const int lane = t & 63;
  const int w = t >> 6;
  const int lm = lane & 15;
  const int q = lane >> 4;
  const int wm = (w & 1) * 64;
  const int wn = (w >> 1) * 64;

  // staging: wave w stages rows [w*32, w*32+32) of each operand, 4 instrs each.
  // lane -> (row_off = l>>3, k-group = (l&7) ^ (l>>3))  [pre-swizzled source]
  const int srow = lane >> 3;
  const int skg = (lane & 7) ^ srow;
  const u16* srcA = Xbm + (size_t)(ti * 128 + w * 32 + srow) * NN + skg * 8;
  const u16* srcB = Xbm + (size_t)(tj * 128 + w * 32 + srow) * NN + skg * 8;
  u16* dstA = &As[(w * 32) * 64];
  u16* dstB = &Bs[(w * 32) * 64];

  f32x4 acc[4][4];
  for (int i = 0; i < 4; i++)
    for (int jj = 0; jj < 4; jj++) { f32x4 z = {0.f, 0.f, 0.f, 0.f}; acc[i][jj] = z; }

  for (int kc = 0; kc < NN / 64; kc++) {
    const int k0 = kc * 64;
    __syncthreads();
#pragma unroll
    for (int ii = 0; ii < 4; ii++)
      gl_lds16(srcA + (size_t)ii * 8 * NN + k0, dstA + ii * 512);
    if (!diag) {
#pragma unroll
      for (int ii = 0; ii < 4; ii++)
        gl_lds16(srcB + (size_t)ii * 8 * NN + k0, dstB + ii * 512);
    }
    __syncthreads();  // drains vmcnt before readers cross
    const u16* Bp = diag ? As : Bs;
#pragma unroll
    for (int kk = 0; kk < 2; kk++) {
      bf16x8 af[4], bfr[4];
      const int gq8 = ((kk * 4 + q) ^ (lm & 7)) * 8;
#pragma unroll
      for (int mt = 0; mt < 4; mt++)
        af[mt] = *(const bf16x8*)&As[(wm + mt * 16 + lm) * 64 + gq8];
#pragma unroll
      for (int nt = 0; nt < 4; nt++)
        bfr[nt] = *(const bf16x8*)&Bp[(wn + nt * 16 + lm) * 64 + gq8];
#pragma unroll
      for (int mt = 0; mt < 4; mt++)
#pragma unroll
        for (int nt = 0; nt < 4; nt++)
          acc[mt][nt] = mfma16(af[mt], bfr[nt], acc[mt][nt]);
    }
  }

  for (int mt = 0; mt < 4; mt++)
    for (int nt = 0; nt < 4; nt++) {
      const int row0 = ti * 128 + wm + mt * 16 + q * 4;
      const int col  = tj * 128 + wn + nt * 16 + lm;
      f32x4 v = acc[mt][nt];
      u16 hi[4], lo[4];
      for (int i = 0; i < 4; i++) split2(v[i], hi[i], lo[i]);
      for (int i = 0; i < 4; i++) {
        Ghb[(size_t)(row0 + i) * CC + col] = hi[i];
        Glb[(size_t)(row0 + i) * CC + col] = lo[i];
      }
      if (!diag) {
        u16x4 ph = {hi[0], hi[1], hi[2], hi[3]};
        u16x4 pl = {lo[0], lo[1], lo[2], lo[3]};
        *(u16x4*)&Ghb[(size_t)col * CC + row0] = ph;
        *(u16x4*)&Glb[(size_t)col * CC + row0] = pl;
      }
    }
}

// ---------------------------------------------------------------------------
// Kernel 2a (ctx1): per (b,modal): U = G_b @ Wv_all  (768x768x768, 3-chain split)
// 128x128 tiles, K-step 64, global_load_lds staging with XOR-swizzle.
// Output: UT split bf16 hi/lo, TRANSPOSED [e][r] (ctx2's B-operand row-major).
// Grid: 1152 blocks, XCD-swizzled (36 tiles of a (b,modal) share an XCD).
// ---------------------------------------------------------------------------
__global__ __launch_bounds__(256) void ctx1_kernel(const u16* __restrict__ WTh,
                                                   const u16* __restrict__ WTl,
                                                   const u16* __restrict__ Gh,
                                                   const u16* __restrict__ Gl,
                                                   u16* __restrict__ UTh,
                                                   u16* __restrict__ UTl) {
  __shared__ __align__(16) u16 lds[32768];  // 64 KB: Ah|Al|Bh|Bl, each [128][64]

  const int dd = blockIdx.x;
  const int j = dd >> 3;
  const int g = (j / 36) * 8 + (dd & 7);  // (b,modal) group 0..31
  const int i = j % 36;
  const int b = g & 15, modal = g >> 4;
  const int ti = i / 6, tj = i % 6;       // r-tile, e-tile

  const size_t goff = (size_t)(modal * BB + b) * CC * CC;
  const u16* Ghb = Gh + goff;
  const u16* Glb = Gl + goff;
  const int vbase = modal * 1536 + 768 + tj * 128;  // WT rows holding Wv^T
  const size_t uoff = (size_t)(modal * BB + b) * CC * CC;

  const int t = threadIdx.x;
  const int lane = t & 63, w = t >> 6;
  const int lm = lane & 15, q = lane >> 4;
  const int wm = (w & 1) * 64, wn = (w >> 1) * 64;

  // staging: wave w stages component w (0=Ah 1=Al 2=Bh 3=Bl), 16x 1KB instrs
  const int srow = lane >> 3;          // 0..7 within 8-row group
  const int sg = (lane & 7) ^ srow;    // pre-swizzled k-group (involution)
  const u16* comp_src;
  if (w < 2) comp_src = (w == 0 ? Ghb : Glb) + (size_t)(ti * 128 + srow) * CC + sg * 8;
  else       comp_src = (w == 2 ? WTh : WTl) + (size_t)(vbase + srow) * CC + sg * 8;
  u16* comp_dst = &lds[w * 8192];

  f32x4 acc[4][4];
  for (int mt = 0; mt < 4; mt++)
    for (int nt = 0; nt < 4; nt++) { f32x4 z = {0.f, 0.f, 0.f, 0.f}; acc[mt][nt] = z; }

  for (int kc = 0; kc < 12; kc++) {
    __syncthreads();
#pragma unroll
    for (int ii = 0; ii < 16; ii++)
      gl_lds16(comp_src + (size_t)ii * 8 * CC + kc * 64, comp_dst + ii * 512);
    __syncthreads();  // drains vmcnt before readers cross
#pragma unroll
    for (int kk = 0; kk < 2; kk++) {
      bf16x8 ah[4], al_[4], bh[4], bl_[4];
      const int gq8 = ((kk * 4 + q) ^ (lm & 7)) * 8;
#pragma unroll
      for (int mt = 0; mt < 4; mt++) {
        const int ro = (wm + mt * 16 + lm) * 64;
        ah[mt]  = *(const bf16x8*)&lds[ro + gq8];
        al_[mt] = *(const bf16x8*)&lds[8192 + ro + gq8];
      }
#pragma unroll
      for (int nt = 0; nt < 4; nt++) {
        const int ro = (wn + nt * 16 + lm) * 64;
        bh[nt]  = *(const bf16x8*)&lds[16384 + ro + gq8];
        bl_[nt] = *(const bf16x8*)&lds[24576 + ro + gq8];
      }
#pragma unroll
      for (int mt = 0; mt < 4; mt++)
#pragma unroll
        for (int nt = 0; nt < 4; nt++) {
          acc[mt][nt] = mfma16(ah[mt], bh[nt], acc[mt][nt]);
          acc[mt][nt] = mfma16(al_[mt], bh[nt], acc[mt][nt]);
          acc[mt][nt] = mfma16(ah[mt], bl_[nt], acc[mt][nt]);
        }
    }
  }

  // epilogue: UT[e][r] split hi/lo (C/D: row=m=r-local=q*4+i, col=n=e-local=lm)
  for (int mt = 0; mt < 4; mt++)
    for (int nt = 0; nt < 4; nt++) {
      const int e = tj * 128 + wn + nt * 16 + lm;
      const int r0 = ti * 128 + wm + mt * 16 + q * 4;
      f32x4 v = acc[mt][nt];
      u16 hi[4], lo[4];
      for (int ii = 0; ii < 4; ii++) split2(v[ii], hi[ii], lo[ii]);
      u16x4 ph = {hi[0], hi[1], hi[2], hi[3]};
      u16x4 pl = {lo[0], lo[1], lo[2], lo[3]};
      *(u16x4*)&UTh[uoff + (size_t)e * CC + r0] = ph;
      *(u16x4*)&UTl[uoff + (size_t)e * CC + r0] = pl;
    }
}

// ---------------------------------------------------------------------------
// Kernel 2b (ctx2): per (b,h,modal): logits = Wk_h^T @ U_h (64x64, K=768),
// pure bf16 split loads (no conversion); scale; softmax over d; ctxT[e][d] bf16.
// ---------------------------------------------------------------------------
__global__ __launch_bounds__(256) void ctx2_kernel(const u16* __restrict__ WTh,
                                                   const u16* __restrict__ WTl,
                                                   const u16* __restrict__ UTh,
                                                   const u16* __restrict__ UTl,
                                                   u16* __restrict__ ctxT) {
  __shared__ float cs[64 * 68];
  const int h = blockIdx.x, b = blockIdx.y, modal = blockIdx.z;
  const size_t uoff = (size_t)(modal * BB + b) * CC * CC;
  const u16* Uh = UTh + uoff + (size_t)(h * HD) * CC;
  const u16* Ul = UTl + uoff + (size_t)(h * HD) * CC;
  const size_t krow = (size_t)modal * 1536 + h * HD;
  u16* cout = ctxT + ((size_t)((modal * BB + b) * HH + h)) * (HD * HD);

  const int t = threadIdx.x;
  const int lane = t & 63, w = t >> 6;
  const int lm = lane & 15, q = lane >> 4;
  const int d0 = w * 16;

  f32x4 acc[4];
  for (int i = 0; i < 4; i++) { f32x4 z = {0.f, 0.f, 0.f, 0.f}; acc[i] = z; }

  const u16* akh = &WTh[(krow + d0 + lm) * CC];
  const u16* akl = &WTl[(krow + d0 + lm) * CC];
  for (int rc = 0; rc < 24; rc++) {
    const int co = rc * 32 + q * 8;
    bf16x8 ah = *(const bf16x8*)&akh[co];
    bf16x8 al = *(const bf16x8*)&akl[co];
#pragma unroll
    for (int nt = 0; nt < 4; nt++) {
      bf16x8 bh = *(const bf16x8*)&Uh[(size_t)(nt * 16 + lm) * CC + co];
      bf16x8 bl = *(const bf16x8*)&Ul[(size_t)(nt * 16 + lm) * CC + co];
      acc[nt] = mfma16(ah, bh, acc[nt]);
      acc[nt] = mfma16(al, bh, acc[nt]);
      acc[nt] = mfma16(ah, bl, acc[nt]);
    }
  }
  // logits: row=m=d-local=q*4+i, col=n=e-local=lm
  for (int nt = 0; nt < 4; nt++) {
    const int e = nt * 16 + lm;
    for (int i = 0; i < 4; i++)
      cs[(d0 + q * 4 + i) * 68 + e] = acc[nt][i] * SCALE_F;
  }
  __syncthreads();
  if (t < 64) {
    const int e = t;
    float mx = -1e30f;
    for (int d = 0; d < 64; d++) mx = fmaxf(mx, cs[d * 68 + e]);
    float s = 0.f;
    for (int d = 0; d < 64; d++) s += __expf(cs[d * 68 + e] - mx);
    const float inv = 1.f / s;
    for (int d = 0; d < 64; d++)
      cout[e * 64 + d] = f2bf(__expf(cs[d * 68 + e] - mx) * inv);  // [e][d]
  }
}

// ---------------------------------------------------------------------------
// Kernel 3: out[modal][b, n, h*64+e] = sum_d X_modal[b,n,h*64+d] * ctx[modal^1][b,h,d,e]
// Reads fp32 X directly (Xbf eliminated); converts during LDS staging.
// ---------------------------------------------------------------------------
__global__ __launch_bounds__(256) void out_kernel(const float* __restrict__ x0,
                                                  const float* __restrict__ x1,
                                                  const u16* __restrict__ ctxT,
                                                  float* __restrict__ out) {
  __shared__ u16 Xs[32 * 776];
  const int nt0 = blockIdx.x;  // 128 tiles of 32 rows
  const int b = blockIdx.y, modal = blockIdx.z;
  const float* X = (modal ? x1 : x0) + (size_t)b * NN * CC + (size_t)nt0 * 32 * CC;
  const u16* ctxb = ctxT + (size_t)(((modal ^ 1) * BB + b) * HH) * (HD * HD);
  float* O = out + (size_t)modal * BB * NN * CC + (size_t)b * NN * CC + (size_t)nt0 * 32 * CC;

  const int t = threadIdx.x;
  for (int idx = t; idx < 32 * 192; idx += 256) {
    const int r = idx / 192, cq = idx % 192;
    float4 v = *(const float4*)&X[(size_t)r * CC + cq * 4];
    u16x4 pk = {f2bf(v.x), f2bf(v.y), f2bf(v.z), f2bf(v.w)};
    *(u16x4*)&Xs[r * 776 + cq * 4] = pk;
  }
  __syncthreads();

  const int lane = t & 63, w = t >> 6;
  const int lm = lane & 15, q = lane >> 4;
  const int mt = w & 1;
  const int hh = (w >> 1) * 6;
  for (int hi = 0; hi < 6; hi++) {
    const int h = hh + hi;
    bf16x8 a0 = *(const bf16x8*)&Xs[(mt * 16 + lm) * 776 + h * 64 + 0 + q * 8];
    bf16x8 a1 = *(const bf16x8*)&Xs[(mt * 16 + lm) * 776 + h * 64 + 32 + q * 8];
    const u16* ch = ctxb + (size_t)h * (HD * HD);
    for (int et = 0; et < 4; et++) {
      f32x4 acc = {0.f, 0.f, 0.f, 0.f};
      bf16x8 b0 = *(const bf16x8*)&ch[(et * 16 + lm) * 64 + 0 + q * 8];
      bf16x8 b1 = *(const bf16x8*)&ch[(et * 16 + lm) * 64 + 32 + q * 8];
      acc = mfma16(a0, b0, acc);
      acc = mfma16(a1, b1, acc);
      for (int i = 0; i < 4; i++)
        O[(size_t)(mt * 16 + q * 4 + i) * CC + h * 64 + et * 16 + lm] = acc[i];
    }
  }
}

// ---------------------------------------------------------------------------
extern "C" void kernel_launch(void* const* d_in, const int* in_sizes, int n_in,
                              void* d_out, int out_size, void* d_ws, size_t ws_size,
                              hipStream_t stream) {
  (void)in_sizes; (void)n_in; (void)out_size; (void)ws_size;
  const float* rgb   = (const float*)d_in[0];
  const float* dep   = (const float*)d_in[1];
  const float* w_rgb = (const float*)d_in[2];
  const float* w_dep = (const float*)d_in[3];
  float* out = (float*)d_out;

  char* ws = (char*)d_ws;
  u16* WTh = (u16*)ws;                       // 4,718,592 B
  u16* WTl = (u16*)(ws + 4718592);           // 4,718,592 B
  u16* Gh  = (u16*)(ws + 9437184);           // 37,748,736 B
  u16* Gl  = (u16*)(ws + 47185920);          // 37,748,736 B
  u16* CT  = (u16*)(ws + 84934656);          // 3,145,728 B
  u16* XbT = (u16*)(ws + 88080384);          // 201,326,592 B
  u16* UTh = (u16*)(ws + 289406976);         // 37,748,736 B
  u16* UTl = (u16*)(ws + 327155712);         // 37,748,736 B -> total 364,904,448 B
                                             // (same footprint round 2 already ran with)

  xcastT_kernel<<<dim3(64, 12, 32), 256, 0, stream>>>(rgb, dep, XbT);
  wtrans_kernel<<<dim3(24, 12, 2), 256, 0, stream>>>(w_rgb, w_dep, WTh, WTl);
  gram_kernel<<<dim3(672, 1, 1), 256, 0, stream>>>(XbT, Gh, Gl);
  ctx1_kernel<<<dim3(1152, 1, 1), 256, 0, stream>>>(WTh, WTl, Gh, Gl, UTh, UTl);
  ctx2_kernel<<<dim3(HH, BB, 2), 256, 0, stream>>>(WTh, WTl, UTh, UTl, CT);
  out_kernel<<<dim3(128, BB, 2), 256, 0, stream>>>(rgb, dep, CT, out);
}